// Round 6
// baseline (287.284 us; speedup 1.0000x reference)
//
#include <hip/hip_runtime.h>
#include <hip/hip_bf16.h>
#include <math.h>

#define N_NODES 100000
#define N_EDGES 400000
#define N_PAIRS 100000
#define NBINS   200000   // (rel, dst) bins

typedef short short8_t __attribute__((ext_vector_type(8)));
typedef float f32x4    __attribute__((ext_vector_type(4)));

__device__ __forceinline__ ushort f2bf(float f) {
    uint u = __float_as_uint(f);
    u += 0x7fffu + ((u >> 16) & 1u);          // RNE
    return (ushort)(u >> 16);
}
__device__ __forceinline__ float bf2f(ushort b) {
    return __uint_as_float(((uint)b) << 16);
}
__device__ __forceinline__ uint packbf(float a, float b) {
    return (uint)f2bf(a) | ((uint)f2bf(b) << 16);
}

#define GLDS16(gp, lp) \
    __builtin_amdgcn_global_load_lds((const __attribute__((address_space(1))) uint*)(gp), \
                                     (__attribute__((address_space(3))) uint*)(lp), 16, 0, 0)

template<int N> __device__ __forceinline__ void waitvm() {
    if constexpr (N == 0)      asm volatile("s_waitcnt vmcnt(0)" ::: "memory");
    else if constexpr (N == 2) asm volatile("s_waitcnt vmcnt(2)" ::: "memory");
    else if constexpr (N == 3) asm volatile("s_waitcnt vmcnt(3)" ::: "memory");
    else if constexpr (N == 4) asm volatile("s_waitcnt vmcnt(4)" ::: "memory");
    else if constexpr (N == 6) asm volatile("s_waitcnt vmcnt(6)" ::: "memory");
    else if constexpr (N == 8) asm volatile("s_waitcnt vmcnt(8)" ::: "memory");
}

// ---------------------------------------------------------------------------
// fp32 -> bf16 cast (vectorized, grid-stride)
// ---------------------------------------------------------------------------
__global__ void cast_kernel(const float* __restrict__ in, ushort* __restrict__ outp, int n4) {
    int i = blockIdx.x * 256 + threadIdx.x;
    int stride = gridDim.x * 256;
    for (; i < n4; i += stride) {
        float4 v = ((const float4*)in)[i];
        ushort4 o;
        o.x = f2bf(v.x); o.y = f2bf(v.y); o.z = f2bf(v.z); o.w = f2bf(v.w);
        ((ushort4*)outp)[i] = o;
    }
}

// ---------------------------------------------------------------------------
// Weight repacks (bf16, K-major rows Wt[n][k])
// ---------------------------------------------------------------------------
__global__ void wlin_kernel(const float* __restrict__ w, ushort* __restrict__ wt, int K) {
    int i = blockIdx.x * 256 + threadIdx.x;    // 128*K
    if (i >= 128 * K) return;
    int n = i / K, k = i - n * K;
    wt[i] = f2bf(w[(size_t)k * 128 + n]);
}
__global__ void wc1_kernel(const float* __restrict__ root, const float* __restrict__ w,
                           ushort* __restrict__ wt) {
    int i = blockIdx.x * 256 + threadIdx.x;    // 256*384
    if (i >= 256 * 384) return;
    int n = i / 384, k = i % 384;
    float v;
    if (k < 128) v = root[(size_t)k * 256 + n];
    else         v = w[(size_t)(k - 128) * 256 + n];   // [2,128,256] contiguous
    wt[(size_t)n * 384 + k] = f2bf(v);
}
__global__ void wc2_kernel(const float* __restrict__ root, const float* __restrict__ w,
                           ushort* __restrict__ wt) {
    int i = blockIdx.x * 256 + threadIdx.x;    // 384*256
    if (i >= 384 * 256) return;
    int n = i / 256, k = i % 256;
    float v;
    if (n < 128) v = root[(size_t)k * 128 + n];
    else         v = w[((size_t)((n >> 7) - 1) * 256 + k) * 128 + (n & 127)];
    wt[(size_t)n * 256 + k] = f2bf(v);
}

// ---------------------------------------------------------------------------
// CSR build: histogram -> exclusive scan (3 kernels) -> fill
// ---------------------------------------------------------------------------
__global__ void hist_kernel(const int* __restrict__ dst, const int* __restrict__ et,
                            int* __restrict__ cnt) {
    int e = blockIdx.x * 256 + threadIdx.x;
    if (e < N_EDGES) atomicAdd(&cnt[et[e] * N_NODES + dst[e]], 1);
}

__global__ __launch_bounds__(1024) void scan1_kernel(const int* __restrict__ cnt,
                                                     int* __restrict__ ptr,
                                                     int* __restrict__ aux) {
    __shared__ int s[1024];
    int i = blockIdx.x * 1024 + threadIdx.x;
    int v = (i < NBINS) ? cnt[i] : 0;
    s[threadIdx.x] = v;
    __syncthreads();
    for (int off = 1; off < 1024; off <<= 1) {
        int t = (threadIdx.x >= off) ? s[threadIdx.x - off] : 0;
        __syncthreads();
        s[threadIdx.x] += t;
        __syncthreads();
    }
    if (i < NBINS) ptr[i] = s[threadIdx.x] - v;          // block-exclusive
    if (threadIdx.x == 1023) aux[blockIdx.x] = s[1023];  // block total
}

__global__ void scan2_kernel(int* __restrict__ aux, int nblk) {
    __shared__ int s[256];
    int v = (threadIdx.x < nblk) ? aux[threadIdx.x] : 0;
    s[threadIdx.x] = v;
    __syncthreads();
    for (int off = 1; off < 256; off <<= 1) {
        int t = (threadIdx.x >= off) ? s[threadIdx.x - off] : 0;
        __syncthreads();
        s[threadIdx.x] += t;
        __syncthreads();
    }
    if (threadIdx.x < nblk) aux[threadIdx.x] = s[threadIdx.x] - v;  // exclusive
}

__global__ void scan3_kernel(const int* __restrict__ aux, int* __restrict__ ptr,
                             int* __restrict__ cursor) {
    int i = blockIdx.x * 256 + threadIdx.x;
    if (i < NBINS) {
        int val = ptr[i] + aux[i >> 10];
        ptr[i] = val;
        cursor[i] = val;
    }
    if (i == 0) ptr[NBINS] = N_EDGES;
}

__global__ void fill_kernel(const int* __restrict__ src, const int* __restrict__ dst,
                            const int* __restrict__ et, int* __restrict__ cursor,
                            int* __restrict__ esorted) {
    int e = blockIdx.x * 256 + threadIdx.x;
    if (e < N_EDGES) {
        int b = et[e] * N_NODES + dst[e];
        int pos = atomicAdd(&cursor[b], 1);
        esorted[pos] = src[e];
    }
}

// ---------------------------------------------------------------------------
// Layer-1 gather-mean: one wave per dst node, both relations, unroll-2.
// ---------------------------------------------------------------------------
__global__ void gather1_kernel(const int* __restrict__ ptr, const int* __restrict__ es,
                               ushort* __restrict__ A1) {
    int d = blockIdx.x * 4 + (threadIdx.x >> 6);
    if (d >= N_NODES) return;
    int lane = threadIdx.x & 63;
    int p0 = ptr[d],           p1 = ptr[d + 1];
    int q0 = ptr[N_NODES + d], q1 = ptr[N_NODES + d + 1];
    int n0 = p1 - p0, n1 = q1 - q0;
    int n  = n0 > n1 ? n0 : n1;
    float a0 = 0, a1 = 0, b0 = 0, b1 = 0;
    for (int k = 0; k < n; k += 2) {
        uint v00 = 0, v01 = 0, v10 = 0, v11 = 0;
        if (k < n0)     v00 = *(const uint*)(A1 + (size_t)es[p0 + k] * 384 + lane * 2);
        if (k + 1 < n0) v01 = *(const uint*)(A1 + (size_t)es[p0 + k + 1] * 384 + lane * 2);
        if (k < n1)     v10 = *(const uint*)(A1 + (size_t)es[q0 + k] * 384 + lane * 2);
        if (k + 1 < n1) v11 = *(const uint*)(A1 + (size_t)es[q0 + k + 1] * 384 + lane * 2);
        a0 += bf2f((ushort)(v00 & 0xffffu)) + bf2f((ushort)(v01 & 0xffffu));
        a1 += bf2f((ushort)(v00 >> 16))     + bf2f((ushort)(v01 >> 16));
        b0 += bf2f((ushort)(v10 & 0xffffu)) + bf2f((ushort)(v11 & 0xffffu));
        b1 += bf2f((ushort)(v10 >> 16))     + bf2f((ushort)(v11 >> 16));
    }
    float i0 = n0 ? 1.0f / (float)n0 : 0.0f;
    float i1 = n1 ? 1.0f / (float)n1 : 0.0f;
    uint* row = (uint*)(A1 + (size_t)d * 384);
    row[64  + lane] = packbf(a0 * i0, a1 * i0);
    row[128 + lane] = packbf(b0 * i1, b1 * i1);
}

// ---------------------------------------------------------------------------
// Layer-2 combine: z[d] = H[d][0:128] + mean_r0 H[s][128:256] + mean_r1 H[s][256:384]
// One wave per dst node, unroll-2. z output bf16.
// ---------------------------------------------------------------------------
__global__ void combine2_kernel(const int* __restrict__ ptr, const int* __restrict__ es,
                                const ushort* __restrict__ H, ushort* __restrict__ zb) {
    int d = blockIdx.x * 4 + (threadIdx.x >> 6);
    if (d >= N_NODES) return;
    int lane = threadIdx.x & 63;
    int p0 = ptr[d],           p1 = ptr[d + 1];
    int q0 = ptr[N_NODES + d], q1 = ptr[N_NODES + d + 1];
    int n0 = p1 - p0, n1 = q1 - q0;
    int n  = n0 > n1 ? n0 : n1;
    uint rv = *(const uint*)(H + (size_t)d * 384 + lane * 2);
    float r0 = bf2f((ushort)(rv & 0xffffu)), r1 = bf2f((ushort)(rv >> 16));
    float a0 = 0, a1 = 0, b0 = 0, b1 = 0;
    for (int k = 0; k < n; k += 2) {
        uint v00 = 0, v01 = 0, v10 = 0, v11 = 0;
        if (k < n0)     v00 = *(const uint*)(H + (size_t)es[p0 + k] * 384 + 128 + lane * 2);
        if (k + 1 < n0) v01 = *(const uint*)(H + (size_t)es[p0 + k + 1] * 384 + 128 + lane * 2);
        if (k < n1)     v10 = *(const uint*)(H + (size_t)es[q0 + k] * 384 + 256 + lane * 2);
        if (k + 1 < n1) v11 = *(const uint*)(H + (size_t)es[q0 + k + 1] * 384 + 256 + lane * 2);
        a0 += bf2f((ushort)(v00 & 0xffffu)) + bf2f((ushort)(v01 & 0xffffu));
        a1 += bf2f((ushort)(v00 >> 16))     + bf2f((ushort)(v01 >> 16));
        b0 += bf2f((ushort)(v10 & 0xffffu)) + bf2f((ushort)(v11 & 0xffffu));
        b1 += bf2f((ushort)(v10 >> 16))     + bf2f((ushort)(v11 >> 16));
    }
    float i0 = n0 ? 1.0f / (float)n0 : 0.0f;
    float i1 = n1 ? 1.0f / (float)n1 : 0.0f;
    uint* orow = (uint*)(zb + (size_t)d * 128);
    orow[lane] = packbf(r0 + a0 * i0 + b0 * i1, r1 + a1 * i0 + b1 * i1);
}

// ---------------------------------------------------------------------------
// Full-N MFMA GEMM: out[row][col] = A[row][:]@Wt[col][:] + bias(col<BIASN).
// Tile 128 x BN (BN = full output width), 8 waves (2x4), wave tile 64 x BN/4.
// 3-slot LDS pipeline, global_load_lds width-16, counted vmcnt (never 0
// mid-loop), XOR-swizzled LDS (pre-swizzled global source + swizzled read).
// ---------------------------------------------------------------------------
template<int KTOT, int BN, int OST, int BIASN, bool RELU>
__global__ __launch_bounds__(512)
void mfma_gemm_kernel(const ushort* __restrict__ A, const ushort* __restrict__ Wt,
                      const float* __restrict__ bias, ushort* __restrict__ outp,
                      int nrows) {
    constexpr int FC = BN / 64;           // frag-cols per wave
    constexpr int LB = BN / 128;          // B loads per thread per K-step
    constexpr int L  = 1 + LB;            // total loads per thread per K-step
    __shared__ short As[3][128 * 32];
    __shared__ short Bs[3][BN * 32];
    const int t  = threadIdx.x;
    const int m0 = blockIdx.x * 128;
    const int lane = t & 63, w = t >> 6;
    const int wr = w >> 2, wcl = w & 3;   // 2 x 4 wave grid
    const int l15 = lane & 15, l4 = lane >> 4;

    // staging: thread t owns A chunk t (row=t>>2, stored chunk t&3) and B
    // chunks t+i*512. Source chunk pre-swizzled: c_log = c_st ^ ((row>>1)&3).
    const int arow = t >> 2;
    const int sw_a = (((t & 3) ^ ((arow >> 1) & 3))) * 8;
    int rg = m0 + arow; if (rg >= nrows) rg = nrows - 1;
    const ushort* ap = A + (size_t)rg * KTOT + sw_a;
    const ushort* bp[LB];
#pragma unroll
    for (int i = 0; i < LB; i++) {
        int ch = t + i * 512;
        int brow = ch >> 2;
        bp[i] = Wt + (size_t)brow * KTOT + (((ch & 3) ^ ((brow >> 1) & 3))) * 8;
    }

#define STAGE(slot, kg) do { \
        GLDS16(ap + (kg), &As[slot][t * 8]); \
        _Pragma("unroll") \
        for (int i_ = 0; i_ < LB; i_++) \
            GLDS16(bp[i_] + (kg), &Bs[slot][(t + i_ * 512) * 8]); \
    } while (0)

    f32x4 acc[4][FC];
#pragma unroll
    for (int j = 0; j < FC; j++) {
        int col = wcl * (FC * 16) + j * 16 + l15;
        float bv = (col < BIASN) ? bias[col] : 0.0f;
        f32x4 tmp = {bv, bv, bv, bv};
#pragma unroll
        for (int i = 0; i < 4; i++) acc[i][j] = tmp;
    }

    // read-side swizzle: logical chunk l4 lives at stored chunk l4^((row>>1)&3),
    // and (row>>1)&3 == (l15>>1)&3 for every fragment row (bases are mult. of 8).
    const int xr = (l4 ^ ((l15 >> 1) & 3)) * 8;

    STAGE(0, 0);
    STAGE(1, 32);
    constexpr int NSTEP = KTOT / 32;
    for (int ks = 0; ks < NSTEP; ks++) {
        const int slot = ks % 3;
        if (ks + 2 < NSTEP) {
            STAGE((ks + 2) % 3, (ks + 2) * 32);
            waitvm<2 * L>();                       // slot ks done; 2 ahead in flight
        } else if (ks + 1 < NSTEP) {
            waitvm<L>();
        } else {
            waitvm<0>();
        }
        asm volatile("s_barrier" ::: "memory");    // slot staged for all waves
        short8_t af[4], bfr[FC];
#pragma unroll
        for (int i = 0; i < 4; i++)
            af[i] = *(short8_t*)&As[slot][(wr * 64 + i * 16 + l15) * 32 + xr];
#pragma unroll
        for (int j = 0; j < FC; j++)
            bfr[j] = *(short8_t*)&Bs[slot][(wcl * (FC * 16) + j * 16 + l15) * 32 + xr];
#pragma unroll
        for (int i = 0; i < 4; i++)
#pragma unroll
            for (int j = 0; j < FC; j++)
                acc[i][j] = __builtin_amdgcn_mfma_f32_16x16x32_bf16(af[i], bfr[j], acc[i][j], 0, 0, 0);
        asm volatile("s_barrier" ::: "memory");    // reads done before slot re-stage
    }
#undef STAGE

#pragma unroll
    for (int i = 0; i < 4; i++) {
#pragma unroll
        for (int r = 0; r < 4; r++) {
            int row = m0 + wr * 64 + i * 16 + l4 * 4 + r;
            if (row < nrows) {
#pragma unroll
                for (int j = 0; j < FC; j++) {
                    int col = wcl * (FC * 16) + j * 16 + l15;
                    float v = acc[i][j][r];
                    if (RELU) v = fmaxf(v, 0.0f);
                    outp[(size_t)row * OST + col] = f2bf(v);
                }
            }
        }
    }
}

// ---------------------------------------------------------------------------
// Decode: out[p] = sigmoid( z[s]·fcw[0:128] + z[d]·fcw[128:256] + fcb ), z bf16
// ---------------------------------------------------------------------------
__global__ void decode_kernel(const ushort* __restrict__ zb, const int* __restrict__ dec,
                              const float* __restrict__ fcw, const float* __restrict__ fcb,
                              float* __restrict__ out) {
    int wid  = blockIdx.x * 4 + (threadIdx.x >> 6);
    int lane = threadIdx.x & 63;
    if (wid >= N_PAIRS) return;
    int s = dec[wid];
    int d = dec[N_PAIRS + wid];
    uint vs = ((const uint*)(zb + (size_t)s * 128))[lane];
    uint vd = ((const uint*)(zb + (size_t)d * 128))[lane];
    float v = bf2f((ushort)(vs & 0xffffu)) * fcw[2 * lane]
            + bf2f((ushort)(vs >> 16))     * fcw[2 * lane + 1]
            + bf2f((ushort)(vd & 0xffffu)) * fcw[128 + 2 * lane]
            + bf2f((ushort)(vd >> 16))     * fcw[128 + 2 * lane + 1];
#pragma unroll
    for (int off = 32; off > 0; off >>= 1) v += __shfl_down(v, off);
    if (lane == 0) out[wid] = 1.0f / (1.0f + expf(-(v + fcb[0])));
}

// ---------------------------------------------------------------------------
extern "C" void kernel_launch(void* const* d_in, const int* in_sizes, int n_in,
                              void* d_out, int out_size, void* d_ws, size_t ws_size,
                              hipStream_t stream) {
    const float* x0        = (const float*)d_in[0];
    const float* x1        = (const float*)d_in[1];
    const int*   edge_idx  = (const int*)  d_in[2];
    const int*   edge_type = (const int*)  d_in[3];
    const int*   dec_index = (const int*)  d_in[4];
    const float* lin0_w    = (const float*)d_in[5];
    const float* lin0_b    = (const float*)d_in[6];
    const float* lin1_w    = (const float*)d_in[7];
    const float* lin1_b    = (const float*)d_in[8];
    const float* conv1_w   = (const float*)d_in[9];
    const float* conv1_root= (const float*)d_in[10];
    const float* conv1_b   = (const float*)d_in[11];
    const float* conv2_w   = (const float*)d_in[12];
    const float* conv2_root= (const float*)d_in[13];
    const float* conv2_b   = (const float*)d_in[14];
    const float* fc_w      = (const float*)d_in[15];
    const float* fc_b      = (const float*)d_in[16];
    float* out = (float*)d_out;

    // ---- workspace layout (bytes), ~151.6 MB; H aliases A1, zb aliases y1 ----
    char* W = (char*)d_ws;
    ushort* A1    = (ushort*)(W + 0);            // 76,800,000 B [100k][384] = [x|agg0|agg1]
    ushort* H     = (ushort*)(W + 0);            // alias (A1 dead after gemm1)
    ushort* y1    = (ushort*)(W + 76800000);     // 51,200,000 B [100k][256]
    ushort* zb    = (ushort*)(W + 76800000);     // alias: [100k][128] bf16 (y1 dead after gemm2)
    int*    cnt   = (int*)   (W + 128000000);
    int*    ptrb  = (int*)   (W + 128800000);
    int*    cursor= (int*)   (W + 129600016);
    int*    aux   = (int*)   (W + 130400016);
    int*    esort = (int*)   (W + 130404112);
    ushort* wc1   = (ushort*)(W + 132004112);    // [256][384] bf16
    ushort* wc2   = (ushort*)(W + 132200720);    // [384][256] bf16
    ushort* wl0   = (ushort*)(W + 132397328);    // [128][128] bf16
    ushort* wl1   = (ushort*)(W + 132430096);    // [128][64]  bf16
    ushort* x0bf  = (ushort*)(W + 132446480);    // [50000][128] bf16
    ushort* x1bf  = (ushort*)(W + 145246480);    // [50000][64]  bf16

    const int* esrc = edge_idx;
    const int* edst = edge_idx + N_EDGES;

    // 0) zero histogram
    hipMemsetAsync(cnt, 0, (size_t)NBINS * sizeof(int), stream);

    // 1) casts + weight repacks
    cast_kernel<<<2048, 256, 0, stream>>>(x0, x0bf, 50000 * 128 / 4);
    cast_kernel<<<2048, 256, 0, stream>>>(x1, x1bf, 50000 * 64 / 4);
    wlin_kernel<<<64, 256, 0, stream>>>(lin0_w, wl0, 128);
    wlin_kernel<<<32, 256, 0, stream>>>(lin1_w, wl1, 64);
    wc1_kernel<<<(256 * 384 + 255) / 256, 256, 0, stream>>>(conv1_root, conv1_w, wc1);
    wc2_kernel<<<(384 * 256 + 255) / 256, 256, 0, stream>>>(conv2_root, conv2_w, wc2);

    // 2) CSR build over (rel,dst)
    hist_kernel<<<(N_EDGES + 255) / 256, 256, 0, stream>>>(edst, edge_type, cnt);
    scan1_kernel<<<(NBINS + 1023) / 1024, 1024, 0, stream>>>(cnt, ptrb, aux);
    scan2_kernel<<<1, 256, 0, stream>>>(aux, (NBINS + 1023) / 1024);
    scan3_kernel<<<(NBINS + 255) / 256, 256, 0, stream>>>(aux, ptrb, cursor);
    fill_kernel<<<(N_EDGES + 255) / 256, 256, 0, stream>>>(esrc, edst, edge_type,
                                                           cursor, esort);

    // 3) input projections via MFMA -> A1 x-slab (cols 0:128, stride 384)
    mfma_gemm_kernel<128, 128, 384, 128, false>
        <<<391, 512, 0, stream>>>(x0bf, wl0, lin0_b, A1, 50000);
    mfma_gemm_kernel<64, 128, 384, 128, false>
        <<<391, 512, 0, stream>>>(x1bf, wl1, lin1_b,
                                  A1 + (size_t)50000 * 384, 50000);

    // 4) layer 1: per-dst gather-mean into A1 agg slabs, then full-N GEMM+ReLU -> y1
    gather1_kernel<<<(N_NODES + 3) / 4, 256, 0, stream>>>(ptrb, esort, A1);
    mfma_gemm_kernel<384, 256, 256, 256, true>
        <<<782, 512, 0, stream>>>(A1, wc1, conv1_b, y1, N_NODES);

    // 5) layer 2: full-N GEMM y1 @ [root2|W0|W1] -> H (aliases A1), then combine -> zb
    mfma_gemm_kernel<256, 384, 384, 128, false>
        <<<782, 512, 0, stream>>>(y1, wc2, conv2_b, H, N_NODES);
    combine2_kernel<<<(N_NODES + 3) / 4, 256, 0, stream>>>(ptrb, esort, H, zb);

    // 6) decode
    decode_kernel<<<(N_PAIRS + 3) / 4, 256, 0, stream>>>(zb, dec_index, fc_w, fc_b, out);
}